// Round 2
// baseline (81.859 us; speedup 1.0000x reference)
//
#include <hip/hip_runtime.h>

// 3-qubit, 2-layer RY/CNOT circuit -> <Z_i> per batch element.
// Algebra (verified in round 1, absmax 0.0039):
//   - layer-0 RY(w[0,i]) folds into encoding RY(x_i*pi): one sincos per wire.
//   - layer-0 CNOTs folded into product-state permutation [0,1,3,2,6,7,5,4].
//   - layer-1 CNOTs folded into the measurement index map.
// This round: 4 rows/thread (2048 blocks = 8/CU), direct v_sin/v_cos in
// revolution domain (range reduction folded into the angle FMA), full-block
// fast path with unconditional float4 epilogue.

__device__ __forceinline__ void qfl_row(
    float4 xv,
    float hw0, float hw1, float hw2,          // encoding offsets (revolutions)
    float c3, float s3, float c4, float s4, float c5, float s5,
    float& o0, float& o1, float& o2)
{
    // x * (3.14159/2 rad) in revolutions = x * 3.14159/(4*pi)
    const float XS = 0.24999948f;
    float ta = fmaf(xv.x, XS, hw0);
    float tb = fmaf(xv.y, XS, hw1);
    float tc = fmaf(xv.z, XS, hw2);
    float a0 = __builtin_amdgcn_cosf(ta), a1 = __builtin_amdgcn_sinf(ta);
    float b0 = __builtin_amdgcn_cosf(tb), b1 = __builtin_amdgcn_sinf(tb);
    float c0 = __builtin_amdgcn_cosf(tc), c1 = __builtin_amdgcn_sinf(tc);

    // product state with layer-0 CNOT(0,1),CNOT(1,2) pre-applied
    float a0b0 = a0 * b0, a0b1 = a0 * b1, a1b0 = a1 * b0, a1b1 = a1 * b1;
    float v0 = a0b0 * c0, v1 = a0b0 * c1;
    float v2 = a0b1 * c1, v3 = a0b1 * c0;
    float v4 = a1b1 * c0, v5 = a1b1 * c1;
    float v6 = a1b0 * c1, v7 = a1b0 * c0;

    // layer-1 RY wire0: pairs (k, k+4)
    { float u, v;
      u = v0; v = v4; v0 = c3*u - s3*v; v4 = s3*u + c3*v;
      u = v1; v = v5; v1 = c3*u - s3*v; v5 = s3*u + c3*v;
      u = v2; v = v6; v2 = c3*u - s3*v; v6 = s3*u + c3*v;
      u = v3; v = v7; v3 = c3*u - s3*v; v7 = s3*u + c3*v; }
    // layer-1 RY wire1: pairs (0,2),(1,3),(4,6),(5,7)
    { float u, v;
      u = v0; v = v2; v0 = c4*u - s4*v; v2 = s4*u + c4*v;
      u = v1; v = v3; v1 = c4*u - s4*v; v3 = s4*u + c4*v;
      u = v4; v = v6; v4 = c4*u - s4*v; v6 = s4*u + c4*v;
      u = v5; v = v7; v5 = c4*u - s4*v; v7 = s4*u + c4*v; }
    // layer-1 RY wire2: pairs (2k, 2k+1)
    { float u, v;
      u = v0; v = v1; v0 = c5*u - s5*v; v1 = s5*u + c5*v;
      u = v2; v = v3; v2 = c5*u - s5*v; v3 = s5*u + c5*v;
      u = v4; v = v5; v4 = c5*u - s5*v; v5 = s5*u + c5*v;
      u = v6; v = v7; v6 = c5*u - s5*v; v7 = s5*u + c5*v; }

    // layer-1 CNOTs folded into measurement: p = f^2, f = [v0,v1,v3,v2,v6,v7,v5,v4]
    float q0 = v0*v0, q1 = v1*v1, q2 = v2*v2, q3 = v3*v3;
    float q4 = v4*v4, q5 = v5*v5, q6 = v6*v6, q7 = v7*v7;
    float e01 = q0 + q1, e23 = q2 + q3, e45 = q4 + q5, e67 = q6 + q7;
    o0 = (e01 + e23) - (e45 + e67);
    o1 = (e01 + e67) - (e23 + e45);
    o2 = (q0 + q3 + q5 + q6) - (q1 + q2 + q4 + q7);
}

__global__ __launch_bounds__(256) void qfl_kernel(
    const float4* __restrict__ x, const float* __restrict__ w,
    float* __restrict__ out, int n)
{
    __shared__ float sout[3072];               // 1024 rows x 3 outputs
    const int tid  = threadIdx.x;
    const int base = blockIdx.x * 1024;        // 4 rows/thread

    // Wave-uniform weight trig; all angles in revolutions (rad * 1/(4*pi)).
    const float R = 0.07957747155f;            // 0.5 rad -> revolutions
    const float hw0 = w[0] * R, hw1 = w[1] * R, hw2 = w[2] * R;
    const float t3 = w[3] * R, t4 = w[4] * R, t5 = w[5] * R;
    const float c3 = __builtin_amdgcn_cosf(t3), s3 = __builtin_amdgcn_sinf(t3);
    const float c4 = __builtin_amdgcn_cosf(t4), s4 = __builtin_amdgcn_sinf(t4);
    const float c5 = __builtin_amdgcn_cosf(t5), s5 = __builtin_amdgcn_sinf(t5);

    const bool full = (base + 1024 <= n);

    float4 xv[4];
    if (full) {
        #pragma unroll
        for (int h = 0; h < 4; ++h) xv[h] = x[base + h * 256 + tid];
    } else {
        #pragma unroll
        for (int h = 0; h < 4; ++h) {
            int e = base + h * 256 + tid;
            xv[h] = (e < n) ? x[e] : make_float4(0.f, 0.f, 0.f, 0.f);
        }
    }

    #pragma unroll
    for (int h = 0; h < 4; ++h) {
        float o0, o1, o2;
        qfl_row(xv[h], hw0, hw1, hw2, c3, s3, c4, s4, c5, s5, o0, o1, o2);
        // stride-3 word writes: 3 coprime with 32 banks -> conflict-free
        sout[h * 768 + 3 * tid + 0] = o0;
        sout[h * 768 + 3 * tid + 1] = o1;
        sout[h * 768 + 3 * tid + 2] = o2;
    }
    __syncthreads();

    if (full) {
        // 3072 floats = 768 float4; 3 fully-coalesced stride-1 stores/thread.
        const float4* s4p = (const float4*)sout;
        float4* og = (float4*)out + (long long)blockIdx.x * 768;
        #pragma unroll
        for (int k = 0; k < 3; ++k) og[k * 256 + tid] = s4p[k * 256 + tid];
    } else {
        // partial tail block: guarded scalar stores
        const long long T  = (long long)n * 3;
        const long long b0 = (long long)base * 3;
        for (int k = tid; k < 3072; k += 256) {
            long long idx = b0 + k;
            if (idx < T) out[idx] = sout[k];
        }
    }
}

extern "C" void kernel_launch(void* const* d_in, const int* in_sizes, int n_in,
                              void* d_out, int out_size, void* d_ws, size_t ws_size,
                              hipStream_t stream) {
    const float4* x = (const float4*)d_in[0];   // (B, 4) float32, row = one float4
    const float*  w = (const float*)d_in[1];    // (2, 3) float32
    float* out = (float*)d_out;                 // (B, 3) float32
    int n = in_sizes[0] / 4;
    int blocks = (n + 1023) / 1024;
    qfl_kernel<<<blocks, 256, 0, stream>>>(x, w, out, n);
}